// Round 9
// baseline (178.145 us; speedup 1.0000x reference)
//
#include <hip/hip_runtime.h>
#include <math.h>

// MultiheadAttention  B=2, T=2048, D=1024, H=16, HD=64, fp32 in/out.
// Round 17: GEMM core pipelined like attn. gemm_core16's 2-barrier K-step
// (barrier -> stage -> barrier+vmcnt(0) drain -> compute) exposes full DMA
// latency every step (~570 TF effective on qkv). New gemm_core32: BK=32,
// two 8KB A/B buffer pairs (32KB total -> occupancy unchanged, m132 trap
// avoided), stage(kt+1) issued BEFORE compute(kt), ONE barrier per step.
// Swizzle for 32-half rows: store col (ks^((r>>1)&3))<<3, read chunk
// quad^((li>>1)&3) -> 2-way bank alias = free. qkv V^T epilogue reuses the
// same 32KB. out_mfma gets the same core. attn/prep unchanged from R16
// (att[2] pipeline, 46us, near structural floor).
// R10-16 carried: register P-transpose, -SOFT_C C-init, XCD swizzles,
// setprio, in-register normalization, no combine kernel.
// Workspace (48MB): xh 8 (->Ctx) | Wqt 2 | Wkt/Wvt/Wot 6 | Qh 8 | Kh 8 |
//                   (spare 8) | Vth 8

#define BATCH 2
#define SEQ   2048
#define DIM   1024
#define NHEAD 16
#define HDIM  64
#define MROWS (BATCH * SEQ)   // 4096
#define BH    (BATCH * NHEAD) // 32
#define NKT   (SEQ / 64)      // 32 K/V tiles, all in one block

typedef __attribute__((ext_vector_type(4))) float     floatx4;
typedef __attribute__((ext_vector_type(4))) float     float4v;
typedef __attribute__((ext_vector_type(8))) _Float16  half8;
typedef __attribute__((ext_vector_type(4))) _Float16  half4;
typedef __attribute__((ext_vector_type(2))) __fp16    fp16x2;
typedef __attribute__((ext_vector_type(4))) unsigned  uint4v;

#define SOFT_C 5.77078016f   // 4*log2e ; p = 2^(s*log2e - 4*log2e) = exp(s-4)
#define QSCALE 0.18033688f   // 0.125 * log2e folded into Q

#if __has_builtin(__builtin_amdgcn_exp2f)
#define EXP2F(x) __builtin_amdgcn_exp2f(x)
#else
#define EXP2F(x) exp2f(x)
#endif

__device__ __forceinline__ void gload16(const void* g, void* l) {
    __builtin_amdgcn_global_load_lds(
        (const __attribute__((address_space(1))) unsigned int*)g,
        (__attribute__((address_space(3))) unsigned int*)l, 16, 0, 0);
}

__device__ __forceinline__ unsigned pk2(float a, float b) {
    fp16x2 v = __builtin_amdgcn_cvt_pkrtz(a, b);
    return __builtin_bit_cast(unsigned, v);
}

// {a,b} <- permlane16_swap(permlane32_swap(a,b)).
// Net: a'' = {A0,A2,B0,B2}, b'' = {A1,A3,B1,B3} (16-lane rows).
__device__ __forceinline__ void plswap(unsigned &a, unsigned &b) {
#if __has_builtin(__builtin_amdgcn_permlane32_swap) && __has_builtin(__builtin_amdgcn_permlane16_swap)
    auto r32 = __builtin_amdgcn_permlane32_swap(a, b, false, false);
    auto r16 = __builtin_amdgcn_permlane16_swap(r32[0], r32[1], false, false);
    a = r16[0]; b = r16[1];
#else
    asm volatile("s_nop 1\n\t"
                 "v_permlane32_swap_b32 %0, %1\n\t"
                 "s_nop 1\n\t"
                 "v_permlane16_swap_b32 %0, %1\n\t"
                 "s_nop 1"
                 : "+v"(a), "+v"(b));
#endif
}

// ---------------- prep: W^T fp16 (z<4) + x fp16 (z==4) ----------------
__global__ __launch_bounds__(256) void prep(
    const float* __restrict__ x,
    const float* __restrict__ Wq, const float* __restrict__ Wk,
    const float* __restrict__ Wv, const float* __restrict__ Wo,
    _Float16* __restrict__ xh,
    _Float16* __restrict__ Wqt, _Float16* __restrict__ Wkt,
    _Float16* __restrict__ Wvt, _Float16* __restrict__ Wot)
{
    const int tid = threadIdx.x;
    if (blockIdx.z == 4) {
        const int bid = blockIdx.y * 16 + blockIdx.x;
        #pragma unroll
        for (int it = 0; it < 8; ++it) {
            const size_t i = (((size_t)it * 256 + bid) * 256 + tid) * 8;
            float4v a = *(const float4v*)(x + i);
            float4v b = *(const float4v*)(x + i + 4);
            half8 o;
            #pragma unroll
            for (int c = 0; c < 4; ++c) { o[c] = (_Float16)a[c]; o[4+c] = (_Float16)b[c]; }
            *(half8*)(xh + i) = o;
        }
        return;
    }
    __shared__ float tile[64][65];
    const float* W; _Float16* o;
    switch (blockIdx.z) {
        case 0: W = Wq; o = Wqt; break;
        case 1: W = Wk; o = Wkt; break;
        case 2: W = Wv; o = Wvt; break;
        default: W = Wo; o = Wot; break;
    }
    const int n0 = blockIdx.x * 64, k0 = blockIdx.y * 64;
    #pragma unroll
    for (int p = 0; p < 16; ++p) {
        int idx = tid + p * 256;
        int r = idx >> 6, c = idx & 63;
        tile[r][c] = W[(size_t)(k0 + r) * DIM + n0 + c];
    }
    __syncthreads();
    #pragma unroll
    for (int p = 0; p < 16; ++p) {
        int idx = tid + p * 256;
        int r = idx >> 6, c = idx & 63;
        o[(size_t)(n0 + r) * DIM + k0 + c] = (_Float16)tile[c][r];
    }
}

// ------ fp16 MFMA GEMM core: 128x128 tile, BK=32, dbuf, 1 barrier/step ----
// AL0/BL0/AL1/BL1: 4 x 4096 halfs (8KB each). Tile layout [128][32] halfs,
// 16B chunks XOR-swizzled by (row>>1)&3 (2-way bank alias = free).
__device__ __forceinline__ void gemm_core32(
    const _Float16* __restrict__ Ap, const _Float16* __restrict__ Bp,
    int m0, int n0, _Float16* SH, floatx4 acc[4][4])
{
    const int tid  = threadIdx.x;
    const int wave = tid >> 6;
    const int lane = tid & 63;
    const int li   = lane & 15;
    const int quad = lane >> 4;
    const int wm   = (wave >> 1) * 64;
    const int wn   = (wave & 1) * 64;

    _Float16* AL0 = SH;
    _Float16* BL0 = SH + 4096;
    _Float16* AL1 = SH + 8192;
    _Float16* BL1 = SH + 12288;

    auto stg = [&](int k0, _Float16* AL, _Float16* BL) {
        #pragma unroll
        for (int p = 0; p < 2; ++p) {
            int s = tid + p * 256;
            int r = s >> 2, ks = s & 3;
            int kg = (ks ^ ((r >> 1) & 3)) << 3;
            int ldsb = (wave * 64 + p * 256) * 8;
            gload16(Ap + (size_t)(m0 + r) * DIM + k0 + kg, AL + ldsb);
            gload16(Bp + (size_t)(n0 + r) * DIM + k0 + kg, BL + ldsb);
        }
    };

    auto cmp = [&](const _Float16* AL, const _Float16* BL) {
        half8 a[4], b[4];
        const int cs = (quad ^ ((li >> 1) & 3)) << 3;
        #pragma unroll
        for (int i = 0; i < 4; ++i) {
            a[i] = *(const half8*)(AL + ((wm + i * 16 + li) << 5) + cs);
            b[i] = *(const half8*)(BL + ((wn + i * 16 + li) << 5) + cs);
        }
        #pragma unroll
        for (int i = 0; i < 4; ++i)
            #pragma unroll
            for (int j = 0; j < 4; ++j)
                acc[i][j] = __builtin_amdgcn_mfma_f32_16x16x32_f16(a[i], b[j], acc[i][j], 0, 0, 0);
    };

    stg(0, AL0, BL0);
    __syncthreads();                        // buffer 0 ready

    for (int kt = 0; kt < DIM / 32; kt += 2) {
        stg((kt + 1) * 32, AL1, BL1);       // flies during compute(kt)
        __builtin_amdgcn_s_setprio(1);
        cmp(AL0, BL0);                      // tile kt
        __builtin_amdgcn_s_setprio(0);
        __syncthreads();                    // buffer 1 ready
        if (kt + 2 < DIM / 32) stg((kt + 2) * 32, AL0, BL0);
        __builtin_amdgcn_s_setprio(1);
        cmp(AL1, BL1);                      // tile kt+1
        __builtin_amdgcn_s_setprio(0);
        __syncthreads();                    // buffer 0 ready (or done)
    }
}

// ---------------- QKV projection (z==2 writes V^T via LDS transpose) ------
__global__ __launch_bounds__(256, 2) void qkv_mfma(
    const _Float16* __restrict__ xh,
    const _Float16* __restrict__ Wqt, const _Float16* __restrict__ Wkt,
    const _Float16* __restrict__ Wvt,
    const float* __restrict__ bq, const float* __restrict__ bk,
    const float* __restrict__ bv,
    _Float16* __restrict__ Qh, _Float16* __restrict__ Kh,
    _Float16* __restrict__ Vth)
{
    // SH: 4 x 8KB A/B dbuf during K-loop; V^T transpose tile (128x128,
    // 16B-chunk XOR swizzle) at epilogue. 32KB exact.
    __shared__ __align__(16) _Float16 SH[128 * 128];

    // XCD-grouping swizzle: nwg = 8*32*3 = 768, cpx = 96
    const int bid = blockIdx.x + 8 * (blockIdx.y + 32 * blockIdx.z);
    const int swz = (bid & 7) * 96 + (bid >> 3);
    const int bx  = swz & 7;
    const int by  = (swz >> 3) & 31;
    const int z   = swz >> 8;

    const _Float16* Bp; const float* bias;
    if (z == 0)      { Bp = Wqt; bias = bq; }
    else if (z == 1) { Bp = Wkt; bias = bk; }
    else             { Bp = Wvt; bias = bv; }

    const int m0 = by * 128, n0 = bx * 128;

    floatx4 acc[4][4];
    #pragma unroll
    for (int i = 0; i < 4; ++i)
        #pragma unroll
        for (int j = 0; j < 4; ++j) acc[i][j] = (floatx4){0.f, 0.f, 0.f, 0.f};

    gemm_core32(xh, Bp, m0, n0, SH, acc);

    const int tid = threadIdx.x, wave = tid >> 6, lane = tid & 63;
    const int li = lane & 15, quad = lane >> 4;
    const int wm = (wave >> 1) * 64, wn = (wave & 1) * 64;
    const int bb = m0 >> 11, t0 = m0 & 2047;   // tile never straddles batch

    if (z != 2) {
        _Float16* out = (z == 0) ? Qh : Kh;
        const float sc = (z == 0) ? QSCALE : 1.0f;   // Q carries 0.125*log2e
        #pragma unroll
        for (int i = 0; i < 4; ++i)
            #pragma unroll
            for (int j = 0; j < 4; ++j) {
                int n = n0 + wn + j * 16 + li;
                int h = n >> 6, hd = n & 63;
                float b_ = bias[n];
                #pragma unroll
                for (int r = 0; r < 4; ++r) {
                    int m = m0 + wm + i * 16 + quad * 4 + r;
                    int t = m & 2047;
                    out[(((size_t)(bb * NHEAD + h) * SEQ) + t) * HDIM + hd] =
                        (_Float16)((acc[i][j][r] + b_) * sc);
                }
            }
    } else {
        // V^T: transpose tile through SH (128x128 halfs = 32KB exact).
        // 16B-chunk XOR swizzle (chunk ^= row&7): writes ~2-way, reads
        // conflict-free, half8 alignment preserved.
        __syncthreads();   // all waves done with dbuf (last core barrier
                           // already synced; this guards SH reuse)
        #pragma unroll
        for (int i = 0; i < 4; ++i)
            #pragma unroll
            for (int j = 0; j < 4; ++j) {
                int n = wn + j * 16 + li;            // feature (row of V^T)
                float b_ = bias[n0 + n];
                half4 w;
                #pragma unroll
                for (int r = 0; r < 4; ++r) w[r] = (_Float16)(acc[i][j][r] + b_);
                int col  = wm + i * 16 + quad * 4;
                int colp = ((((col >> 3) ^ (n & 7)) << 3)) | (col & 7);
                *(half4*)(SH + n * 128 + colp) = w;
            }
        __syncthreads();
        #pragma unroll
        for (int p = 0; p < 8; ++p) {
            int idx = p * 256 + tid;
            int v = idx >> 4, c8 = (idx & 15) * 8;   // row, chunk
            int c8p = (((c8 >> 3) ^ (v & 7)) << 3);
            half8 w = *(const half8*)(SH + v * 128 + c8p);
            int n = n0 + v;
            int h = n >> 6, hd = n & 63;
            *(half8*)(Vth + ((size_t)(bb * NHEAD + h) * HDIM + hd) * SEQ + t0 + c8) = w;
        }
    }
}

// ---------------- Flash attention: pipelined PV (att[2]), 256 thr --------
// grid (SEQ/128, BH) = 512 blocks, XCD-grouped. Per kt-phase: PV+rowsum of
// tile kt-1 (registers only) interleaves with QK^T->exp->permlane of tile
// kt; V-frags of kt pulled to registers before the barrier so the 2-buffer
// LDS recycles exactly as before. Normalized Ctx written directly.
__global__ __launch_bounds__(256, 2) void attn(
    const _Float16* __restrict__ Q, const _Float16* __restrict__ K,
    const _Float16* __restrict__ Vt,
    _Float16* __restrict__ Ctx)
{
    __shared__ __align__(16) _Float16 Ks[2][64 * 64];
    __shared__ __align__(16) _Float16 Vs[2][64 * 64];

    const int tid  = threadIdx.x;
    const int wave = tid >> 6;
    const int lane = tid & 63;
    const int li   = lane & 15;
    const int quad = lane >> 4;

    // XCD-grouping swizzle: nwg = 16*32 = 512, cpx = 64. 16 q-tile blocks
    // sharing a bh K/V panel land on the same XCD's L2.
    const int bid = blockIdx.x + 16 * blockIdx.y;
    const int swz = (bid & 7) * 64 + (bid >> 3);
    const int q0  = (swz & 15) * 128;
    const int bh  = swz >> 4;
    const int b   = bh >> 4, h = bh & 15;

    half8 qa[2][2];
    #pragma unroll
    for (int nq = 0; nq < 2; ++nq) {
        size_t qrow = ((size_t)bh * SEQ + q0 + wave * 32 + nq * 16 + li) * HDIM;
        qa[nq][0] = *(const half8*)(Q + qrow + quad * 8);
        qa[nq][1] = *(const half8*)(Q + qrow + 32 + quad * 8);
    }

    // ones A-fragment: row 0 (li==0) = 1.0 -> accumulator row0 = row-sums
    half8 onesA;
    {
        _Float16 v = (li == 0) ? (_Float16)1.0f : (_Float16)0.0f;
        #pragma unroll
        for (int c = 0; c < 8; ++c) onesA[c] = v;
    }

    floatx4 O[4][2];
    floatx4 rsacc[2];
    #pragma unroll
    for (int nq = 0; nq < 2; ++nq) {
        rsacc[nq] = (floatx4){0.f, 0.f, 0.f, 0.f};
        #pragma unroll
        for (int i = 0; i < 4; ++i) O[i][nq] = (floatx4){0.f, 0.f, 0.f, 0.f};
    }

    const _Float16* Kbh = K  + (size_t)bh * SEQ * HDIM;
    const _Float16* Vbh = Vt + (size_t)bh * HDIM * SEQ;

    auto stage = [&](int buf, int kt_) {
        const _Float16* Kg = Kbh + (size_t)kt_ * 64 * HDIM;
        const _Float16* Vg = Vbh + kt_ * 64;
        _Float16* Kl = &Ks[buf][0];
        _Float16* Vl = &Vs[buf][0];
        #pragma unroll
        for (int p = 0; p < 2; ++p) {
            int s = tid + p * 256;
            int r = s >> 3, ks = s & 7;
            int kg = (ks ^ (r & 7)) << 3;
            int ldsb = (wave * 64 + p * 256) * 8;
            gload16(Kg + r * HDIM + kg, Kl + ldsb);
            gload16(Vg + (size_t)r * SEQ + kg, Vl + ldsb);
        }
    };

    // QK^T -> exp -> permlane -> pbN ; V-frags -> vfN (registers)
    auto qk_phase = [&](const _Float16* Kc, const _Float16* Vc,
                        half8 (&pbN)[2][2], half8 (&vfN)[4][2]) {
        unsigned R[2][4][2];
        #pragma unroll
        for (int mb = 0; mb < 4; ++mb) {
            int row = (mb * 16 + li) << 6;
            half8 a0 = *(const half8*)(Kc + row + ((quad ^ (li & 7)) << 3));
            half8 a1 = *(const half8*)(Kc + row + (((quad + 4) ^ (li & 7)) << 3));
            #pragma unroll
            for (int nq = 0; nq < 2; ++nq) {
                floatx4 st = (floatx4){-SOFT_C, -SOFT_C, -SOFT_C, -SOFT_C};
                st = __builtin_amdgcn_mfma_f32_16x16x32_f16(a0, qa[nq][0], st, 0, 0, 0);
                st = __builtin_amdgcn_mfma_f32_16x16x32_f16(a1, qa[nq][1], st, 0, 0, 0);
                R[nq][mb][0] = pk2(EXP2F(st[0]), EXP2F(st[1]));
                R[nq][mb][1] = pk2(EXP2F(st[2]), EXP2F(st[3]));
            }
        }
        #pragma unroll
        for (int nq = 0; nq < 2; ++nq)
            #pragma unroll
            for (int f = 0; f < 2; ++f) {
                unsigned w0, w1, w2, w3;
                {
                    unsigned x = R[nq][2 * f][0], y = R[nq][2 * f + 1][0];
                    plswap(x, y);
                    w0 = x; w2 = y;
                }
                {
                    unsigned x = R[nq][2 * f][1], y = R[nq][2 * f + 1][1];
                    plswap(x, y);
                    w1 = x; w3 = y;
                }
                uint4v uw; uw[0] = w0; uw[1] = w1; uw[2] = w2; uw[3] = w3;
                pbN[nq][f] = __builtin_bit_cast(half8, uw);
            }
        #pragma unroll
        for (int mb = 0; mb < 4; ++mb) {
            int row = (mb * 16 + li) << 6;
            vfN[mb][0] = *(const half8*)(Vc + row + ((quad ^ (li & 7)) << 3));
            vfN[mb][1] = *(const half8*)(Vc + row + (((quad + 4) ^ (li & 7)) << 3));
        }
    };

    // rowsum + PV of the previous tile (registers only)
    auto pv_phase = [&](half8 (&pbP)[2][2], half8 (&vfP)[4][2]) {
        #pragma unroll
        for (int nq = 0; nq < 2; ++nq) {
            rsacc[nq] = __builtin_amdgcn_mfma_f32_16x16x32_f16(onesA, pbP[nq][0], rsacc[nq], 0, 0, 0);
            rsacc[nq] = __builtin_amdgcn_mfma_f32_16x16x32_f16(onesA, pbP[nq][1], rsacc[nq], 0, 0, 0);
        }
        #pragma unroll
        for (int mb = 0; mb < 4; ++mb)
            #pragma unroll
            for (int nq = 0; nq < 2; ++nq) {
                O[mb][nq] = __builtin_amdgcn_mfma_f32_16x16x32_f16(vfP[mb][0], pbP[nq][0], O[mb][nq], 0, 0, 0);
                O[mb][nq] = __builtin_amdgcn_mfma_f32_16x16x32_f16(vfP[mb][1], pbP[nq][1], O[mb][nq], 0, 0, 0);
            }
    };

    half8 pbA[2][2], pbB[2][2];
    half8 vfA[4][2], vfB[4][2];

    stage(0, 0);
    __syncthreads();                       // buffer 0 ready

    // kt = 0 (buffer 0 -> A), no PV yet
    stage(1, 1);
    __builtin_amdgcn_s_setprio(1);
    qk_phase(&Ks[0][0], &Vs[0][0], pbA, vfA);
    __builtin_amdgcn_s_setprio(0);
    __syncthreads();                       // buffer 1 ready

    // pairs (kt odd -> B, kt+1 even -> A), kt = 1..29
    for (int kt = 1; kt < NKT - 1; kt += 2) {
        stage(0, kt + 1);                  // even tile -> buffer 0
        __builtin_amdgcn_s_setprio(1);
        pv_phase(pbA, vfA);                // tile kt-1 (even)
        qk_phase(&Ks[1][0], &Vs[1][0], pbB, vfB);   // tile kt (odd)
        __builtin_amdgcn_s_setprio(0);
        __syncthreads();

        stage(1, kt + 2);                  // odd tile -> buffer 1
        __builtin_amdgcn_s_setprio(1);
        pv_phase(pbB, vfB);                // tile kt (odd)
        qk_phase(&Ks[0][0], &Vs[0][0], pbA, vfA);   // tile kt+1 (even)
        __builtin_amdgcn_s_setprio(0);
        __syncthreads();
    }

    // tail: kt = 31 (buffer 1 -> B), then drain
    __builtin_amdgcn_s_setprio(1);
    pv_phase(pbA, vfA);                    // tile 30
    qk_phase(&Ks[1][0], &Vs[1][0], pbB, vfB);       // tile 31
    pv_phase(pbB, vfB);                    // tile 31
    __builtin_amdgcn_s_setprio(0);
    __syncthreads();                       // all waves done with K/V LDS

    // full row sums: accumulator row 0 = (quad 0, reg 0), col = query li.
    // Broadcast to all quads of the same li, then normalize in-register.
    float inv[2];
    #pragma unroll
    for (int nq = 0; nq < 2; ++nq) {
        float rs = __shfl(rsacc[nq][0], li, 64);
        inv[nq] = 1.0f / rs;
    }

    // normalized O^T -> XOR-swizzled stride-64 transpose in dead Ks,
    // then coalesced half8 stores along hd. 4KB scratch per wave.
    _Float16* Sw = &Ks[0][0] + wave * (32 * 64);
    #pragma unroll
    for (int mb = 0; mb < 4; ++mb)
        #pragma unroll
        for (int nq = 0; nq < 2; ++nq) {
            uint2 w;
            w.x = pk2(O[mb][nq][0] * inv[nq], O[mb][nq][1] * inv[nq]);
            w.y = pk2(O[mb][nq][2] * inv[nq], O[mb][nq][3] * inv[nq]);
            int row = nq * 16 + li;             // q within wave tile
            int col = mb * 16 + quad * 4;       // hd
            int swc = (((col >> 3) ^ (row & 7)) << 3) | (col & 7);
            *(uint2*)(Sw + row * 64 + swc) = w;
        }
    __builtin_amdgcn_s_waitcnt(0);   // own ds_writes complete (wave-local)
    #pragma unroll
    for (int p = 0; p < 4; ++p) {
        int idx = p * 64 + lane;
        int qq = idx >> 3, c = idx & 7;
        half8 v = *(const half8*)(Sw + qq * 64 + ((c ^ (qq & 7)) << 3));
        size_t row = (size_t)b * SEQ + q0 + wave * 32 + qq;
        *(half8*)(Ctx + row * DIM + h * HDIM + c * 8) = v;
    }
}

// ---------------- Output projection (fp16 MFMA, fp32 out) ----------------
__global__ __launch_bounds__(256, 2) void out_mfma(
    const _Float16* __restrict__ Ctx, const _Float16* __restrict__ Wot,
    const float* __restrict__ bo, float* __restrict__ out)
{
    __shared__ __align__(16) _Float16 SH[4 * 4096];   // 32KB dbuf

    // XCD-grouping swizzle: nwg = 8*32 = 256, cpx = 32
    const int bid = blockIdx.x + 8 * blockIdx.y;
    const int swz = (bid & 7) * 32 + (bid >> 3);
    const int m0 = (swz >> 3) * 128, n0 = (swz & 7) * 128;

    floatx4 acc[4][4];
    #pragma unroll
    for (int i = 0; i < 4; ++i)
        #pragma unroll
        for (int j = 0; j < 4; ++j) acc[i][j] = (floatx4){0.f, 0.f, 0.f, 0.f};

    gemm_core32(Ctx, Wot, m0, n0, SH, acc);

    const int tid = threadIdx.x, wave = tid >> 6, lane = tid & 63;
    const int li = lane & 15, quad = lane >> 4;
    const int wm = (wave >> 1) * 64, wn = (wave & 1) * 64;

    #pragma unroll
    for (int i = 0; i < 4; ++i)
        #pragma unroll
        for (int j = 0; j < 4; ++j) {
            int n = n0 + wn + j * 16 + li;
            float b_ = bo[n];
            #pragma unroll
            for (int r = 0; r < 4; ++r) {
                int m = m0 + wm + i * 16 + quad * 4 + r;
                out[(size_t)m * DIM + n] = acc[i][j][r] + b_;
            }
        }
}

extern "C" void kernel_launch(void* const* d_in, const int* in_sizes, int n_in,
                              void* d_out, int out_size, void* d_ws, size_t ws_size,
                              hipStream_t stream) {
    const float* x  = (const float*)d_in[0];
    const float* Wq = (const float*)d_in[1];
    const float* bq = (const float*)d_in[2];
    const float* Wk = (const float*)d_in[3];
    const float* bk = (const float*)d_in[4];
    const float* Wv = (const float*)d_in[5];
    const float* bv = (const float*)d_in[6];
    const float* Wo = (const float*)d_in[7];
    const float* bo = (const float*)d_in[8];
    float* out = (float*)d_out;

    const size_t PX = (size_t)MROWS * DIM;   // 4M
    const size_t PW = (size_t)DIM * DIM;     // 1M
    _Float16* xh  = (_Float16*)d_ws;         // later Ctx
    _Float16* Wqt = xh + PX;
    _Float16* Wkt = Wqt + PW;
    _Float16* Wvt = Wkt + PW;
    _Float16* Wot = Wvt + PW;
    _Float16* Qh  = Wot + PW;
    _Float16* Kh  = Qh + PX;
    _Float16* spare = Kh + PX;
    _Float16* Vth = spare + PX;

    _Float16* Ctx = xh;

    prep<<<dim3(16, 16, 5), 256, 0, stream>>>(
        x, Wq, Wk, Wv, Wo, xh, Wqt, Wkt, Wvt, Wot);

    qkv_mfma<<<dim3(DIM / 128, MROWS / 128, 3), 256, 0, stream>>>(
        xh, Wqt, Wkt, Wvt, bq, bk, bv, Qh, Kh, Vth);

    attn<<<dim3(SEQ / 128, BH), 256, 0, stream>>>(
        Qh, Kh, Vth, Ctx);

    out_mfma<<<dim3(DIM / 128, MROWS / 128), 256, 0, stream>>>(
        Ctx, Wot, bo, out);
}

// Round 10
// 176.690 us; speedup vs baseline: 1.0082x; 1.0082x over previous
//
#include <hip/hip_runtime.h>
#include <math.h>

// MultiheadAttention  B=2, T=2048, D=1024, H=16, HD=64, fp32 in/out.
// Round 18: block-level TLP fixes (the one repeatedly-verified lever).
// R17 post-mortem: pipelined GEMM core flat -> at >=2 blocks/CU inter-block
// overlap already hides staging (m99/m100 lesson); qkv was never the stall
// I modeled. Where TLP DOES bind: (1) out_mfma grid 256 = 1 block/CU, zero
// cross-coverage (R12's collapse mechanism) -> now 64x128 tiles, grid 512,
// BK=64 dbuf (48KB), 2-3 blocks/CU; (2) qkv 768 blocks at 2/CU = 1.5
// dispatch rounds -> launch_bounds (256,3) lifts to 3/CU = exactly 1.0
// rounds (LDS 32KB allows 5; ~170 VGPR cap, no spill at ~120 used).
// attn/prep unchanged from R16 (att[2] pipeline, 46us floor).
// R10-17 carried: register P-transpose, -SOFT_C C-init, XCD swizzles,
// setprio, in-register normalization, no combine kernel, gemm_core32 dbuf.
// Workspace (48MB): xh 8 (->Ctx) | Wqt 2 | Wkt/Wvt/Wot 6 | Qh 8 | Kh 8 |
//                   (spare 8) | Vth 8

#define BATCH 2
#define SEQ   2048
#define DIM   1024
#define NHEAD 16
#define HDIM  64
#define MROWS (BATCH * SEQ)   // 4096
#define BH    (BATCH * NHEAD) // 32
#define NKT   (SEQ / 64)      // 32 K/V tiles, all in one block

typedef __attribute__((ext_vector_type(4))) float     floatx4;
typedef __attribute__((ext_vector_type(4))) float     float4v;
typedef __attribute__((ext_vector_type(8))) _Float16  half8;
typedef __attribute__((ext_vector_type(4))) _Float16  half4;
typedef __attribute__((ext_vector_type(2))) __fp16    fp16x2;
typedef __attribute__((ext_vector_type(4))) unsigned  uint4v;

#define SOFT_C 5.77078016f   // 4*log2e ; p = 2^(s*log2e - 4*log2e) = exp(s-4)
#define QSCALE 0.18033688f   // 0.125 * log2e folded into Q

#if __has_builtin(__builtin_amdgcn_exp2f)
#define EXP2F(x) __builtin_amdgcn_exp2f(x)
#else
#define EXP2F(x) exp2f(x)
#endif

__device__ __forceinline__ void gload16(const void* g, void* l) {
    __builtin_amdgcn_global_load_lds(
        (const __attribute__((address_space(1))) unsigned int*)g,
        (__attribute__((address_space(3))) unsigned int*)l, 16, 0, 0);
}

__device__ __forceinline__ unsigned pk2(float a, float b) {
    fp16x2 v = __builtin_amdgcn_cvt_pkrtz(a, b);
    return __builtin_bit_cast(unsigned, v);
}

// {a,b} <- permlane16_swap(permlane32_swap(a,b)).
// Net: a'' = {A0,A2,B0,B2}, b'' = {A1,A3,B1,B3} (16-lane rows).
__device__ __forceinline__ void plswap(unsigned &a, unsigned &b) {
#if __has_builtin(__builtin_amdgcn_permlane32_swap) && __has_builtin(__builtin_amdgcn_permlane16_swap)
    auto r32 = __builtin_amdgcn_permlane32_swap(a, b, false, false);
    auto r16 = __builtin_amdgcn_permlane16_swap(r32[0], r32[1], false, false);
    a = r16[0]; b = r16[1];
#else
    asm volatile("s_nop 1\n\t"
                 "v_permlane32_swap_b32 %0, %1\n\t"
                 "s_nop 1\n\t"
                 "v_permlane16_swap_b32 %0, %1\n\t"
                 "s_nop 1"
                 : "+v"(a), "+v"(b));
#endif
}

// ---------------- prep: W^T fp16 (z<4) + x fp16 (z==4) ----------------
__global__ __launch_bounds__(256) void prep(
    const float* __restrict__ x,
    const float* __restrict__ Wq, const float* __restrict__ Wk,
    const float* __restrict__ Wv, const float* __restrict__ Wo,
    _Float16* __restrict__ xh,
    _Float16* __restrict__ Wqt, _Float16* __restrict__ Wkt,
    _Float16* __restrict__ Wvt, _Float16* __restrict__ Wot)
{
    const int tid = threadIdx.x;
    if (blockIdx.z == 4) {
        const int bid = blockIdx.y * 16 + blockIdx.x;
        #pragma unroll
        for (int it = 0; it < 8; ++it) {
            const size_t i = (((size_t)it * 256 + bid) * 256 + tid) * 8;
            float4v a = *(const float4v*)(x + i);
            float4v b = *(const float4v*)(x + i + 4);
            half8 o;
            #pragma unroll
            for (int c = 0; c < 4; ++c) { o[c] = (_Float16)a[c]; o[4+c] = (_Float16)b[c]; }
            *(half8*)(xh + i) = o;
        }
        return;
    }
    __shared__ float tile[64][65];
    const float* W; _Float16* o;
    switch (blockIdx.z) {
        case 0: W = Wq; o = Wqt; break;
        case 1: W = Wk; o = Wkt; break;
        case 2: W = Wv; o = Wvt; break;
        default: W = Wo; o = Wot; break;
    }
    const int n0 = blockIdx.x * 64, k0 = blockIdx.y * 64;
    #pragma unroll
    for (int p = 0; p < 16; ++p) {
        int idx = tid + p * 256;
        int r = idx >> 6, c = idx & 63;
        tile[r][c] = W[(size_t)(k0 + r) * DIM + n0 + c];
    }
    __syncthreads();
    #pragma unroll
    for (int p = 0; p < 16; ++p) {
        int idx = tid + p * 256;
        int r = idx >> 6, c = idx & 63;
        o[(size_t)(n0 + r) * DIM + k0 + c] = (_Float16)tile[c][r];
    }
}

// ------ fp16 MFMA GEMM core: 128x128 tile, BK=32, dbuf, 1 barrier/step ----
// AL0/BL0/AL1/BL1: 4 x 4096 halfs (8KB each). Tile layout [128][32] halfs,
// 16B chunks XOR-swizzled by (row>>1)&3 (2-way bank alias = free).
__device__ __forceinline__ void gemm_core32(
    const _Float16* __restrict__ Ap, const _Float16* __restrict__ Bp,
    int m0, int n0, _Float16* SH, floatx4 acc[4][4])
{
    const int tid  = threadIdx.x;
    const int wave = tid >> 6;
    const int lane = tid & 63;
    const int li   = lane & 15;
    const int quad = lane >> 4;
    const int wm   = (wave >> 1) * 64;
    const int wn   = (wave & 1) * 64;

    _Float16* AL0 = SH;
    _Float16* BL0 = SH + 4096;
    _Float16* AL1 = SH + 8192;
    _Float16* BL1 = SH + 12288;

    auto stg = [&](int k0, _Float16* AL, _Float16* BL) {
        #pragma unroll
        for (int p = 0; p < 2; ++p) {
            int s = tid + p * 256;
            int r = s >> 2, ks = s & 3;
            int kg = (ks ^ ((r >> 1) & 3)) << 3;
            int ldsb = (wave * 64 + p * 256) * 8;
            gload16(Ap + (size_t)(m0 + r) * DIM + k0 + kg, AL + ldsb);
            gload16(Bp + (size_t)(n0 + r) * DIM + k0 + kg, BL + ldsb);
        }
    };

    auto cmp = [&](const _Float16* AL, const _Float16* BL) {
        half8 a[4], b[4];
        const int cs = (quad ^ ((li >> 1) & 3)) << 3;
        #pragma unroll
        for (int i = 0; i < 4; ++i) {
            a[i] = *(const half8*)(AL + ((wm + i * 16 + li) << 5) + cs);
            b[i] = *(const half8*)(BL + ((wn + i * 16 + li) << 5) + cs);
        }
        #pragma unroll
        for (int i = 0; i < 4; ++i)
            #pragma unroll
            for (int j = 0; j < 4; ++j)
                acc[i][j] = __builtin_amdgcn_mfma_f32_16x16x32_f16(a[i], b[j], acc[i][j], 0, 0, 0);
    };

    stg(0, AL0, BL0);
    __syncthreads();                        // buffer 0 ready

    for (int kt = 0; kt < DIM / 32; kt += 2) {
        stg((kt + 1) * 32, AL1, BL1);       // flies during compute(kt)
        __builtin_amdgcn_s_setprio(1);
        cmp(AL0, BL0);                      // tile kt
        __builtin_amdgcn_s_setprio(0);
        __syncthreads();                    // buffer 1 ready
        if (kt + 2 < DIM / 32) stg((kt + 2) * 32, AL0, BL0);
        __builtin_amdgcn_s_setprio(1);
        cmp(AL1, BL1);                      // tile kt+1
        __builtin_amdgcn_s_setprio(0);
        __syncthreads();                    // buffer 0 ready (or done)
    }
}

// ---------------- QKV projection (z==2 writes V^T via LDS transpose) ------
// (256,3): 3 blocks/CU -> 768 blocks = exactly 1 dispatch round.
__global__ __launch_bounds__(256, 3) void qkv_mfma(
    const _Float16* __restrict__ xh,
    const _Float16* __restrict__ Wqt, const _Float16* __restrict__ Wkt,
    const _Float16* __restrict__ Wvt,
    const float* __restrict__ bq, const float* __restrict__ bk,
    const float* __restrict__ bv,
    _Float16* __restrict__ Qh, _Float16* __restrict__ Kh,
    _Float16* __restrict__ Vth)
{
    // SH: 4 x 8KB A/B dbuf during K-loop; V^T transpose tile (128x128,
    // 16B-chunk XOR swizzle) at epilogue. 32KB exact.
    __shared__ __align__(16) _Float16 SH[128 * 128];

    // XCD-grouping swizzle: nwg = 8*32*3 = 768, cpx = 96
    const int bid = blockIdx.x + 8 * (blockIdx.y + 32 * blockIdx.z);
    const int swz = (bid & 7) * 96 + (bid >> 3);
    const int bx  = swz & 7;
    const int by  = (swz >> 3) & 31;
    const int z   = swz >> 8;

    const _Float16* Bp; const float* bias;
    if (z == 0)      { Bp = Wqt; bias = bq; }
    else if (z == 1) { Bp = Wkt; bias = bk; }
    else             { Bp = Wvt; bias = bv; }

    const int m0 = by * 128, n0 = bx * 128;

    floatx4 acc[4][4];
    #pragma unroll
    for (int i = 0; i < 4; ++i)
        #pragma unroll
        for (int j = 0; j < 4; ++j) acc[i][j] = (floatx4){0.f, 0.f, 0.f, 0.f};

    gemm_core32(xh, Bp, m0, n0, SH, acc);

    const int tid = threadIdx.x, wave = tid >> 6, lane = tid & 63;
    const int li = lane & 15, quad = lane >> 4;
    const int wm = (wave >> 1) * 64, wn = (wave & 1) * 64;
    const int bb = m0 >> 11, t0 = m0 & 2047;   // tile never straddles batch

    if (z != 2) {
        _Float16* out = (z == 0) ? Qh : Kh;
        const float sc = (z == 0) ? QSCALE : 1.0f;   // Q carries 0.125*log2e
        #pragma unroll
        for (int i = 0; i < 4; ++i)
            #pragma unroll
            for (int j = 0; j < 4; ++j) {
                int n = n0 + wn + j * 16 + li;
                int h = n >> 6, hd = n & 63;
                float b_ = bias[n];
                #pragma unroll
                for (int r = 0; r < 4; ++r) {
                    int m = m0 + wm + i * 16 + quad * 4 + r;
                    int t = m & 2047;
                    out[(((size_t)(bb * NHEAD + h) * SEQ) + t) * HDIM + hd] =
                        (_Float16)((acc[i][j][r] + b_) * sc);
                }
            }
    } else {
        // V^T: transpose tile through SH (128x128 halfs = 32KB exact).
        // 16B-chunk XOR swizzle (chunk ^= row&7): writes ~2-way, reads
        // conflict-free, half8 alignment preserved.
        __syncthreads();   // guards SH reuse after the core's last barrier
        #pragma unroll
        for (int i = 0; i < 4; ++i)
            #pragma unroll
            for (int j = 0; j < 4; ++j) {
                int n = wn + j * 16 + li;            // feature (row of V^T)
                float b_ = bias[n0 + n];
                half4 w;
                #pragma unroll
                for (int r = 0; r < 4; ++r) w[r] = (_Float16)(acc[i][j][r] + b_);
                int col  = wm + i * 16 + quad * 4;
                int colp = ((((col >> 3) ^ (n & 7)) << 3)) | (col & 7);
                *(half4*)(SH + n * 128 + colp) = w;
            }
        __syncthreads();
        #pragma unroll
        for (int p = 0; p < 8; ++p) {
            int idx = p * 256 + tid;
            int v = idx >> 4, c8 = (idx & 15) * 8;   // row, chunk
            int c8p = (((c8 >> 3) ^ (v & 7)) << 3);
            half8 w = *(const half8*)(SH + v * 128 + c8p);
            int n = n0 + v;
            int h = n >> 6, hd = n & 63;
            *(half8*)(Vth + ((size_t)(bb * NHEAD + h) * HDIM + hd) * SEQ + t0 + c8) = w;
        }
    }
}

// ---------------- Flash attention: pipelined PV (att[2]), 256 thr --------
// grid (SEQ/128, BH) = 512 blocks, XCD-grouped. Per kt-phase: PV+rowsum of
// tile kt-1 (registers only) interleaves with QK^T->exp->permlane of tile
// kt; V-frags of kt pulled to registers before the barrier so the 2-buffer
// LDS recycles exactly as before. Normalized Ctx written directly.
__global__ __launch_bounds__(256, 2) void attn(
    const _Float16* __restrict__ Q, const _Float16* __restrict__ K,
    const _Float16* __restrict__ Vt,
    _Float16* __restrict__ Ctx)
{
    __shared__ __align__(16) _Float16 Ks[2][64 * 64];
    __shared__ __align__(16) _Float16 Vs[2][64 * 64];

    const int tid  = threadIdx.x;
    const int wave = tid >> 6;
    const int lane = tid & 63;
    const int li   = lane & 15;
    const int quad = lane >> 4;

    // XCD-grouping swizzle: nwg = 16*32 = 512, cpx = 64. 16 q-tile blocks
    // sharing a bh K/V panel land on the same XCD's L2.
    const int bid = blockIdx.x + 16 * blockIdx.y;
    const int swz = (bid & 7) * 64 + (bid >> 3);
    const int q0  = (swz & 15) * 128;
    const int bh  = swz >> 4;
    const int b   = bh >> 4, h = bh & 15;

    half8 qa[2][2];
    #pragma unroll
    for (int nq = 0; nq < 2; ++nq) {
        size_t qrow = ((size_t)bh * SEQ + q0 + wave * 32 + nq * 16 + li) * HDIM;
        qa[nq][0] = *(const half8*)(Q + qrow + quad * 8);
        qa[nq][1] = *(const half8*)(Q + qrow + 32 + quad * 8);
    }

    // ones A-fragment: row 0 (li==0) = 1.0 -> accumulator row0 = row-sums
    half8 onesA;
    {
        _Float16 v = (li == 0) ? (_Float16)1.0f : (_Float16)0.0f;
        #pragma unroll
        for (int c = 0; c < 8; ++c) onesA[c] = v;
    }

    floatx4 O[4][2];
    floatx4 rsacc[2];
    #pragma unroll
    for (int nq = 0; nq < 2; ++nq) {
        rsacc[nq] = (floatx4){0.f, 0.f, 0.f, 0.f};
        #pragma unroll
        for (int i = 0; i < 4; ++i) O[i][nq] = (floatx4){0.f, 0.f, 0.f, 0.f};
    }

    const _Float16* Kbh = K  + (size_t)bh * SEQ * HDIM;
    const _Float16* Vbh = Vt + (size_t)bh * HDIM * SEQ;

    auto stage = [&](int buf, int kt_) {
        const _Float16* Kg = Kbh + (size_t)kt_ * 64 * HDIM;
        const _Float16* Vg = Vbh + kt_ * 64;
        _Float16* Kl = &Ks[buf][0];
        _Float16* Vl = &Vs[buf][0];
        #pragma unroll
        for (int p = 0; p < 2; ++p) {
            int s = tid + p * 256;
            int r = s >> 3, ks = s & 7;
            int kg = (ks ^ (r & 7)) << 3;
            int ldsb = (wave * 64 + p * 256) * 8;
            gload16(Kg + r * HDIM + kg, Kl + ldsb);
            gload16(Vg + (size_t)r * SEQ + kg, Vl + ldsb);
        }
    };

    // QK^T -> exp -> permlane -> pbN ; V-frags -> vfN (registers)
    auto qk_phase = [&](const _Float16* Kc, const _Float16* Vc,
                        half8 (&pbN)[2][2], half8 (&vfN)[4][2]) {
        unsigned R[2][4][2];
        #pragma unroll
        for (int mb = 0; mb < 4; ++mb) {
            int row = (mb * 16 + li) << 6;
            half8 a0 = *(const half8*)(Kc + row + ((quad ^ (li & 7)) << 3));
            half8 a1 = *(const half8*)(Kc + row + (((quad + 4) ^ (li & 7)) << 3));
            #pragma unroll
            for (int nq = 0; nq < 2; ++nq) {
                floatx4 st = (floatx4){-SOFT_C, -SOFT_C, -SOFT_C, -SOFT_C};
                st = __builtin_amdgcn_mfma_f32_16x16x32_f16(a0, qa[nq][0], st, 0, 0, 0);
                st = __builtin_amdgcn_mfma_f32_16x16x32_f16(a1, qa[nq][1], st, 0, 0, 0);
                R[nq][mb][0] = pk2(EXP2F(st[0]), EXP2F(st[1]));
                R[nq][mb][1] = pk2(EXP2F(st[2]), EXP2F(st[3]));
            }
        }
        #pragma unroll
        for (int nq = 0; nq < 2; ++nq)
            #pragma unroll
            for (int f = 0; f < 2; ++f) {
                unsigned w0, w1, w2, w3;
                {
                    unsigned x = R[nq][2 * f][0], y = R[nq][2 * f + 1][0];
                    plswap(x, y);
                    w0 = x; w2 = y;
                }
                {
                    unsigned x = R[nq][2 * f][1], y = R[nq][2 * f + 1][1];
                    plswap(x, y);
                    w1 = x; w3 = y;
                }
                uint4v uw; uw[0] = w0; uw[1] = w1; uw[2] = w2; uw[3] = w3;
                pbN[nq][f] = __builtin_bit_cast(half8, uw);
            }
        #pragma unroll
        for (int mb = 0; mb < 4; ++mb) {
            int row = (mb * 16 + li) << 6;
            vfN[mb][0] = *(const half8*)(Vc + row + ((quad ^ (li & 7)) << 3));
            vfN[mb][1] = *(const half8*)(Vc + row + (((quad + 4) ^ (li & 7)) << 3));
        }
    };

    // rowsum + PV of the previous tile (registers only)
    auto pv_phase = [&](half8 (&pbP)[2][2], half8 (&vfP)[4][2]) {
        #pragma unroll
        for (int nq = 0; nq < 2; ++nq) {
            rsacc[nq] = __builtin_amdgcn_mfma_f32_16x16x32_f16(onesA, pbP[nq][0], rsacc[nq], 0, 0, 0);
            rsacc[nq] = __builtin_amdgcn_mfma_f32_16x16x32_f16(onesA, pbP[nq][1], rsacc[nq], 0, 0, 0);
        }
        #pragma unroll
        for (int mb = 0; mb < 4; ++mb)
            #pragma unroll
            for (int nq = 0; nq < 2; ++nq) {
                O[mb][nq] = __builtin_amdgcn_mfma_f32_16x16x32_f16(vfP[mb][0], pbP[nq][0], O[mb][nq], 0, 0, 0);
                O[mb][nq] = __builtin_amdgcn_mfma_f32_16x16x32_f16(vfP[mb][1], pbP[nq][1], O[mb][nq], 0, 0, 0);
            }
    };

    half8 pbA[2][2], pbB[2][2];
    half8 vfA[4][2], vfB[4][2];

    stage(0, 0);
    __syncthreads();                       // buffer 0 ready

    // kt = 0 (buffer 0 -> A), no PV yet
    stage(1, 1);
    __builtin_amdgcn_s_setprio(1);
    qk_phase(&Ks[0][0], &Vs[0][0], pbA, vfA);
    __builtin_amdgcn_s_setprio(0);
    __syncthreads();                       // buffer 1 ready

    // pairs (kt odd -> B, kt+1 even -> A), kt = 1..29
    for (int kt = 1; kt < NKT - 1; kt += 2) {
        stage(0, kt + 1);                  // even tile -> buffer 0
        __builtin_amdgcn_s_setprio(1);
        pv_phase(pbA, vfA);                // tile kt-1 (even)
        qk_phase(&Ks[1][0], &Vs[1][0], pbB, vfB);   // tile kt (odd)
        __builtin_amdgcn_s_setprio(0);
        __syncthreads();

        stage(1, kt + 2);                  // odd tile -> buffer 1
        __builtin_amdgcn_s_setprio(1);
        pv_phase(pbB, vfB);                // tile kt (odd)
        qk_phase(&Ks[0][0], &Vs[0][0], pbA, vfA);   // tile kt+1 (even)
        __builtin_amdgcn_s_setprio(0);
        __syncthreads();
    }

    // tail: kt = 31 (buffer 1 -> B), then drain
    __builtin_amdgcn_s_setprio(1);
    pv_phase(pbA, vfA);                    // tile 30
    qk_phase(&Ks[1][0], &Vs[1][0], pbB, vfB);       // tile 31
    pv_phase(pbB, vfB);                    // tile 31
    __builtin_amdgcn_s_setprio(0);
    __syncthreads();                       // all waves done with K/V LDS

    // full row sums: accumulator row 0 = (quad 0, reg 0), col = query li.
    // Broadcast to all quads of the same li, then normalize in-register.
    float inv[2];
    #pragma unroll
    for (int nq = 0; nq < 2; ++nq) {
        float rs = __shfl(rsacc[nq][0], li, 64);
        inv[nq] = 1.0f / rs;
    }

    // normalized O^T -> XOR-swizzled stride-64 transpose in dead Ks,
    // then coalesced half8 stores along hd. 4KB scratch per wave.
    _Float16* Sw = &Ks[0][0] + wave * (32 * 64);
    #pragma unroll
    for (int mb = 0; mb < 4; ++mb)
        #pragma unroll
        for (int nq = 0; nq < 2; ++nq) {
            uint2 w;
            w.x = pk2(O[mb][nq][0] * inv[nq], O[mb][nq][1] * inv[nq]);
            w.y = pk2(O[mb][nq][2] * inv[nq], O[mb][nq][3] * inv[nq]);
            int row = nq * 16 + li;             // q within wave tile
            int col = mb * 16 + quad * 4;       // hd
            int swc = (((col >> 3) ^ (row & 7)) << 3) | (col & 7);
            *(uint2*)(Sw + row * 64 + swc) = w;
        }
    __builtin_amdgcn_s_waitcnt(0);   // own ds_writes complete (wave-local)
    #pragma unroll
    for (int p = 0; p < 4; ++p) {
        int idx = p * 64 + lane;
        int qq = idx >> 3, c = idx & 7;
        half8 v = *(const half8*)(Sw + qq * 64 + ((c ^ (qq & 7)) << 3));
        size_t row = (size_t)b * SEQ + q0 + wave * 32 + qq;
        *(half8*)(Ctx + row * DIM + h * HDIM + c * 8) = v;
    }
}

// ---------------- Output projection: 64x128 tiles, dbuf BK=64 -------------
// grid (8, 64) = 512 blocks -> 2-3 blocks/CU (was 256 = 1/CU, zero
// inter-block overlap). Waves 2x2, each 32x64 (acc[2][4]). LDS 48KB:
// A0 8 | B0 16 | A1 8 | B1 16. One barrier per K-step.
__global__ __launch_bounds__(256, 3) void out_mfma(
    const _Float16* __restrict__ Ctx, const _Float16* __restrict__ Wot,
    const float* __restrict__ bo, float* __restrict__ out)
{
    __shared__ __align__(16) _Float16 SH[24576];   // 48KB

    // XCD swizzle: nwg = 512, cpx = 64; per XCD: by in one 8-group, all bx
    // -> 8 A-panels (1MB) + full Wot (2MB) < 4MB L2.
    const int bid = blockIdx.x + 8 * blockIdx.y;
    const int swz = (bid & 7) * 64 + (bid >> 3);
    const int bx = swz & 7, by = swz >> 3;
    const int m0 = by * 64, n0 = bx * 128;

    const int tid  = threadIdx.x;
    const int wave = tid >> 6;
    const int lane = tid & 63;
    const int li   = lane & 15;
    const int quad = lane >> 4;
    const int wm   = (wave >> 1) * 32;
    const int wn   = (wave & 1) * 64;

    _Float16* A0 = SH;
    _Float16* B0 = SH + 4096;
    _Float16* A1 = SH + 12288;
    _Float16* B1 = SH + 16384;

    floatx4 acc[2][4];
    #pragma unroll
    for (int i = 0; i < 2; ++i)
        #pragma unroll
        for (int j = 0; j < 4; ++j) acc[i][j] = (floatx4){0.f, 0.f, 0.f, 0.f};

    auto stg = [&](int k0, _Float16* AL, _Float16* BL) {
        #pragma unroll
        for (int p = 0; p < 2; ++p) {        // A: 64 rows x 64 k = 8KB
            int s = tid + p * 256;
            int r = s >> 3, ks = s & 7;
            int kg = (ks ^ (r & 7)) << 3;
            gload16(Ctx + (size_t)(m0 + r) * DIM + k0 + kg,
                    AL + (wave * 64 + p * 256) * 8);
        }
        #pragma unroll
        for (int p = 0; p < 4; ++p) {        // B: 128 rows x 64 k = 16KB
            int s = tid + p * 256;
            int r = s >> 3, ks = s & 7;
            int kg = (ks ^ (r & 7)) << 3;
            gload16(Wot + (size_t)(n0 + r) * DIM + k0 + kg,
                    BL + (wave * 64 + p * 256) * 8);
        }
    };

    auto cmp = [&](const _Float16* AL, const _Float16* BL) {
        half8 a[2][2], b[4][2];
        #pragma unroll
        for (int i = 0; i < 2; ++i) {
            int ra = (wm + i * 16 + li) << 6;
            #pragma unroll
            for (int hh = 0; hh < 2; ++hh)
                a[i][hh] = *(const half8*)(AL + ra + (((hh * 4 + quad) ^ (li & 7)) << 3));
        }
        #pragma unroll
        for (int j = 0; j < 4; ++j) {
            int rb = (wn + j * 16 + li) << 6;
            #pragma unroll
            for (int hh = 0; hh < 2; ++hh)
                b[j][hh] = *(const half8*)(BL + rb + (((hh * 4 + quad) ^ (li & 7)) << 3));
        }
        #pragma unroll
        for (int i = 0; i < 2; ++i)
            #pragma unroll
            for (int j = 0; j < 4; ++j) {
                acc[i][j] = __builtin_amdgcn_mfma_f32_16x16x32_f16(a[i][0], b[j][0], acc[i][j], 0, 0, 0);
                acc[i][j] = __builtin_amdgcn_mfma_f32_16x16x32_f16(a[i][1], b[j][1], acc[i][j], 0, 0, 0);
            }
    };

    stg(0, A0, B0);
    __syncthreads();
    for (int kt = 0; kt < DIM / 64; kt += 2) {
        stg((kt + 1) * 64, A1, B1);
        __builtin_amdgcn_s_setprio(1);
        cmp(A0, B0);
        __builtin_amdgcn_s_setprio(0);
        __syncthreads();
        if (kt + 2 < DIM / 64) stg((kt + 2) * 64, A0, B0);
        __builtin_amdgcn_s_setprio(1);
        cmp(A1, B1);
        __builtin_amdgcn_s_setprio(0);
        __syncthreads();
    }

    #pragma unroll
    for (int i = 0; i < 2; ++i)
        #pragma unroll
        for (int j = 0; j < 4; ++j) {
            int n = n0 + wn + j * 16 + li;
            float b_ = bo[n];
            #pragma unroll
            for (int r = 0; r < 4; ++r) {
                int m = m0 + wm + i * 16 + quad * 4 + r;
                out[(size_t)m * DIM + n] = acc[i][j][r] + b_;
            }
        }
}

extern "C" void kernel_launch(void* const* d_in, const int* in_sizes, int n_in,
                              void* d_out, int out_size, void* d_ws, size_t ws_size,
                              hipStream_t stream) {
    const float* x  = (const float*)d_in[0];
    const float* Wq = (const float*)d_in[1];
    const float* bq = (const float*)d_in[2];
    const float* Wk = (const float*)d_in[3];
    const float* bk = (const float*)d_in[4];
    const float* Wv = (const float*)d_in[5];
    const float* bv = (const float*)d_in[6];
    const float* Wo = (const float*)d_in[7];
    const float* bo = (const float*)d_in[8];
    float* out = (float*)d_out;

    const size_t PX = (size_t)MROWS * DIM;   // 4M
    const size_t PW = (size_t)DIM * DIM;     // 1M
    _Float16* xh  = (_Float16*)d_ws;         // later Ctx
    _Float16* Wqt = xh + PX;
    _Float16* Wkt = Wqt + PW;
    _Float16* Wvt = Wkt + PW;
    _Float16* Wot = Wvt + PW;
    _Float16* Qh  = Wot + PW;
    _Float16* Kh  = Qh + PX;
    _Float16* spare = Kh + PX;
    _Float16* Vth = spare + PX;

    _Float16* Ctx = xh;

    prep<<<dim3(16, 16, 5), 256, 0, stream>>>(
        x, Wq, Wk, Wv, Wo, xh, Wqt, Wkt, Wvt, Wot);

    qkv_mfma<<<dim3(DIM / 128, MROWS / 128, 3), 256, 0, stream>>>(
        xh, Wqt, Wkt, Wvt, bq, bk, bv, Qh, Kh, Vth);

    attn<<<dim3(SEQ / 128, BH), 256, 0, stream>>>(
        Qh, Kh, Vth, Ctx);

    out_mfma<<<dim3(8, MROWS / 64), 256, 0, stream>>>(
        Ctx, Wot, bo, out);
}

// Round 12
// 173.114 us; speedup vs baseline: 1.0291x; 1.0207x over previous
//
#include <hip/hip_runtime.h>
#include <math.h>

// MultiheadAttention  B=2, T=2048, D=1024, H=16, HD=64, fp32 in/out.
// Round 20: RESUBMIT of R19 (bench infra failed twice; no measurement).
// Re-audited: barriers uniform, V tri-buffer rotation correct (traced
// phases 0-15), V-swizzle algebra resolves to global chunk kc*4+quad,
// LDS 80KB @ (256,2) = 160KB/CU exact. Theory unchanged:
// attn KVBLK 64->128 (16 phases, was 32) halves the per-phase
// __syncthreads drain (each barrier = compiler vmcnt(0) convoy of all 4
// waves). att[2] pipeline kept: PV(kt-1)+rowsum interleave with
// QK(kt)->exp->permlane. PV reads V-frags from LDS (not registers) ->
// V triple-buffer (3x16KB) + K double-buffer (2x16KB) = 80KB, 2 blocks/CU
// (grid 512 = 2/CU). Buffer rotation via LDS POINTERS (rule #20); pb in
// named A/B sets via x2-unrolled phase loop.
// prep/qkv/out unchanged from R18 (each < 45us, below attn in profile).
// R10-18 carried: register P-transpose, -SOFT_C C-init, XCD swizzles,
// setprio, in-register normalization, no combine, dbuf GEMM cores.
// Workspace (48MB): xh 8 (->Ctx) | Wqt 2 | Wkt/Wvt/Wot 6 | Qh 8 | Kh 8 |
//                   (spare 8) | Vth 8

#define BATCH 2
#define SEQ   2048
#define DIM   1024
#define NHEAD 16
#define HDIM  64
#define MROWS (BATCH * SEQ)   // 4096
#define BH    (BATCH * NHEAD) // 32
#define KVB   128
#define NKT2  (SEQ / KVB)     // 16 K/V tiles, all in one block

typedef __attribute__((ext_vector_type(4))) float     floatx4;
typedef __attribute__((ext_vector_type(4))) float     float4v;
typedef __attribute__((ext_vector_type(8))) _Float16  half8;
typedef __attribute__((ext_vector_type(4))) _Float16  half4;
typedef __attribute__((ext_vector_type(2))) __fp16    fp16x2;
typedef __attribute__((ext_vector_type(4))) unsigned  uint4v;

#define SOFT_C 5.77078016f   // 4*log2e ; p = 2^(s*log2e - 4*log2e) = exp(s-4)
#define QSCALE 0.18033688f   // 0.125 * log2e folded into Q

#if __has_builtin(__builtin_amdgcn_exp2f)
#define EXP2F(x) __builtin_amdgcn_exp2f(x)
#else
#define EXP2F(x) exp2f(x)
#endif

__device__ __forceinline__ void gload16(const void* g, void* l) {
    __builtin_amdgcn_global_load_lds(
        (const __attribute__((address_space(1))) unsigned int*)g,
        (__attribute__((address_space(3))) unsigned int*)l, 16, 0, 0);
}

__device__ __forceinline__ unsigned pk2(float a, float b) {
    fp16x2 v = __builtin_amdgcn_cvt_pkrtz(a, b);
    return __builtin_bit_cast(unsigned, v);
}

// {a,b} <- permlane16_swap(permlane32_swap(a,b)).
// Net: a'' = {A0,A2,B0,B2}, b'' = {A1,A3,B1,B3} (16-lane rows).
__device__ __forceinline__ void plswap(unsigned &a, unsigned &b) {
#if __has_builtin(__builtin_amdgcn_permlane32_swap) && __has_builtin(__builtin_amdgcn_permlane16_swap)
    auto r32 = __builtin_amdgcn_permlane32_swap(a, b, false, false);
    auto r16 = __builtin_amdgcn_permlane16_swap(r32[0], r32[1], false, false);
    a = r16[0]; b = r16[1];
#else
    asm volatile("s_nop 1\n\t"
                 "v_permlane32_swap_b32 %0, %1\n\t"
                 "s_nop 1\n\t"
                 "v_permlane16_swap_b32 %0, %1\n\t"
                 "s_nop 1"
                 : "+v"(a), "+v"(b));
#endif
}

// ---------------- prep: W^T fp16 (z<4) + x fp16 (z==4) ----------------
__global__ __launch_bounds__(256) void prep(
    const float* __restrict__ x,
    const float* __restrict__ Wq, const float* __restrict__ Wk,
    const float* __restrict__ Wv, const float* __restrict__ Wo,
    _Float16* __restrict__ xh,
    _Float16* __restrict__ Wqt, _Float16* __restrict__ Wkt,
    _Float16* __restrict__ Wvt, _Float16* __restrict__ Wot)
{
    const int tid = threadIdx.x;
    if (blockIdx.z == 4) {
        const int bid = blockIdx.y * 16 + blockIdx.x;
        #pragma unroll
        for (int it = 0; it < 8; ++it) {
            const size_t i = (((size_t)it * 256 + bid) * 256 + tid) * 8;
            float4v a = *(const float4v*)(x + i);
            float4v b = *(const float4v*)(x + i + 4);
            half8 o;
            #pragma unroll
            for (int c = 0; c < 4; ++c) { o[c] = (_Float16)a[c]; o[4+c] = (_Float16)b[c]; }
            *(half8*)(xh + i) = o;
        }
        return;
    }
    __shared__ float tile[64][65];
    const float* W; _Float16* o;
    switch (blockIdx.z) {
        case 0: W = Wq; o = Wqt; break;
        case 1: W = Wk; o = Wkt; break;
        case 2: W = Wv; o = Wvt; break;
        default: W = Wo; o = Wot; break;
    }
    const int n0 = blockIdx.x * 64, k0 = blockIdx.y * 64;
    #pragma unroll
    for (int p = 0; p < 16; ++p) {
        int idx = tid + p * 256;
        int r = idx >> 6, c = idx & 63;
        tile[r][c] = W[(size_t)(k0 + r) * DIM + n0 + c];
    }
    __syncthreads();
    #pragma unroll
    for (int p = 0; p < 16; ++p) {
        int idx = tid + p * 256;
        int r = idx >> 6, c = idx & 63;
        o[(size_t)(n0 + r) * DIM + k0 + c] = (_Float16)tile[c][r];
    }
}

// ------ fp16 MFMA GEMM core: 128x128 tile, BK=32, dbuf, 1 barrier/step ----
// AL0/BL0/AL1/BL1: 4 x 4096 halfs (8KB each). Tile layout [128][32] halfs,
// 16B chunks XOR-swizzled by (row>>1)&3 (2-way bank alias = free).
__device__ __forceinline__ void gemm_core32(
    const _Float16* __restrict__ Ap, const _Float16* __restrict__ Bp,
    int m0, int n0, _Float16* SH, floatx4 acc[4][4])
{
    const int tid  = threadIdx.x;
    const int wave = tid >> 6;
    const int lane = tid & 63;
    const int li   = lane & 15;
    const int quad = lane >> 4;
    const int wm   = (wave >> 1) * 64;
    const int wn   = (wave & 1) * 64;

    _Float16* AL0 = SH;
    _Float16* BL0 = SH + 4096;
    _Float16* AL1 = SH + 8192;
    _Float16* BL1 = SH + 12288;

    auto stg = [&](int k0, _Float16* AL, _Float16* BL) {
        #pragma unroll
        for (int p = 0; p < 2; ++p) {
            int s = tid + p * 256;
            int r = s >> 2, ks = s & 3;
            int kg = (ks ^ ((r >> 1) & 3)) << 3;
            int ldsb = (wave * 64 + p * 256) * 8;
            gload16(Ap + (size_t)(m0 + r) * DIM + k0 + kg, AL + ldsb);
            gload16(Bp + (size_t)(n0 + r) * DIM + k0 + kg, BL + ldsb);
        }
    };

    auto cmp = [&](const _Float16* AL, const _Float16* BL) {
        half8 a[4], b[4];
        const int cs = (quad ^ ((li >> 1) & 3)) << 3;
        #pragma unroll
        for (int i = 0; i < 4; ++i) {
            a[i] = *(const half8*)(AL + ((wm + i * 16 + li) << 5) + cs);
            b[i] = *(const half8*)(BL + ((wn + i * 16 + li) << 5) + cs);
        }
        #pragma unroll
        for (int i = 0; i < 4; ++i)
            #pragma unroll
            for (int j = 0; j < 4; ++j)
                acc[i][j] = __builtin_amdgcn_mfma_f32_16x16x32_f16(a[i], b[j], acc[i][j], 0, 0, 0);
    };

    stg(0, AL0, BL0);
    __syncthreads();                        // buffer 0 ready

    for (int kt = 0; kt < DIM / 32; kt += 2) {
        stg((kt + 1) * 32, AL1, BL1);       // flies during compute(kt)
        __builtin_amdgcn_s_setprio(1);
        cmp(AL0, BL0);                      // tile kt
        __builtin_amdgcn_s_setprio(0);
        __syncthreads();                    // buffer 1 ready
        if (kt + 2 < DIM / 32) stg((kt + 2) * 32, AL0, BL0);
        __builtin_amdgcn_s_setprio(1);
        cmp(AL1, BL1);                      // tile kt+1
        __builtin_amdgcn_s_setprio(0);
        __syncthreads();                    // buffer 0 ready (or done)
    }
}

// ---------------- QKV projection (z==2 writes V^T via LDS transpose) ------
// (256,3): 3 blocks/CU -> 768 blocks = exactly 1 dispatch round.
__global__ __launch_bounds__(256, 3) void qkv_mfma(
    const _Float16* __restrict__ xh,
    const _Float16* __restrict__ Wqt, const _Float16* __restrict__ Wkt,
    const _Float16* __restrict__ Wvt,
    const float* __restrict__ bq, const float* __restrict__ bk,
    const float* __restrict__ bv,
    _Float16* __restrict__ Qh, _Float16* __restrict__ Kh,
    _Float16* __restrict__ Vth)
{
    // SH: 4 x 8KB A/B dbuf during K-loop; V^T transpose tile (128x128,
    // 16B-chunk XOR swizzle) at epilogue. 32KB exact.
    __shared__ __align__(16) _Float16 SH[128 * 128];

    // XCD-grouping swizzle: nwg = 8*32*3 = 768, cpx = 96
    const int bid = blockIdx.x + 8 * (blockIdx.y + 32 * blockIdx.z);
    const int swz = (bid & 7) * 96 + (bid >> 3);
    const int bx  = swz & 7;
    const int by  = (swz >> 3) & 31;
    const int z   = swz >> 8;

    const _Float16* Bp; const float* bias;
    if (z == 0)      { Bp = Wqt; bias = bq; }
    else if (z == 1) { Bp = Wkt; bias = bk; }
    else             { Bp = Wvt; bias = bv; }

    const int m0 = by * 128, n0 = bx * 128;

    floatx4 acc[4][4];
    #pragma unroll
    for (int i = 0; i < 4; ++i)
        #pragma unroll
        for (int j = 0; j < 4; ++j) acc[i][j] = (floatx4){0.f, 0.f, 0.f, 0.f};

    gemm_core32(xh, Bp, m0, n0, SH, acc);

    const int tid = threadIdx.x, wave = tid >> 6, lane = tid & 63;
    const int li = lane & 15, quad = lane >> 4;
    const int wm = (wave >> 1) * 64, wn = (wave & 1) * 64;
    const int bb = m0 >> 11, t0 = m0 & 2047;   // tile never straddles batch

    if (z != 2) {
        _Float16* out = (z == 0) ? Qh : Kh;
        const float sc = (z == 0) ? QSCALE : 1.0f;   // Q carries 0.125*log2e
        #pragma unroll
        for (int i = 0; i < 4; ++i)
            #pragma unroll
            for (int j = 0; j < 4; ++j) {
                int n = n0 + wn + j * 16 + li;
                int h = n >> 6, hd = n & 63;
                float b_ = bias[n];
                #pragma unroll
                for (int r = 0; r < 4; ++r) {
                    int m = m0 + wm + i * 16 + quad * 4 + r;
                    int t = m & 2047;
                    out[(((size_t)(bb * NHEAD + h) * SEQ) + t) * HDIM + hd] =
                        (_Float16)((acc[i][j][r] + b_) * sc);
                }
            }
    } else {
        // V^T: transpose tile through SH (128x128 halfs = 32KB exact).
        // 16B-chunk XOR swizzle (chunk ^= row&7): writes ~2-way, reads
        // conflict-free, half8 alignment preserved.
        __syncthreads();   // guards SH reuse after the core's last barrier
        #pragma unroll
        for (int i = 0; i < 4; ++i)
            #pragma unroll
            for (int j = 0; j < 4; ++j) {
                int n = wn + j * 16 + li;            // feature (row of V^T)
                float b_ = bias[n0 + n];
                half4 w;
                #pragma unroll
                for (int r = 0; r < 4; ++r) w[r] = (_Float16)(acc[i][j][r] + b_);
                int col  = wm + i * 16 + quad * 4;
                int colp = ((((col >> 3) ^ (n & 7)) << 3)) | (col & 7);
                *(half4*)(SH + n * 128 + colp) = w;
            }
        __syncthreads();
        #pragma unroll
        for (int p = 0; p < 8; ++p) {
            int idx = p * 256 + tid;
            int v = idx >> 4, c8 = (idx & 15) * 8;   // row, chunk
            int c8p = (((c8 >> 3) ^ (v & 7)) << 3);
            half8 w = *(const half8*)(SH + v * 128 + c8p);
            int n = n0 + v;
            int h = n >> 6, hd = n & 63;
            *(half8*)(Vth + ((size_t)(bb * NHEAD + h) * HDIM + hd) * SEQ + t0 + c8) = w;
        }
    }
}

// ---------------- Flash attention: KVB=128, att[2], V from LDS -----------
// grid (SEQ/128, BH) = 512 blocks, XCD-grouped. 16 phases; per phase:
// stage(kt+1) -> {K dbuf, V tri-buf}; PV+rowsum of tile kt-1 (pb regs +
// V-frags straight from LDS tri-buffer); QK^T->exp->permlane of tile kt.
// One barrier per phase (was 2 tiles/2 barriers per 128 keys before).
__global__ __launch_bounds__(256, 2) void attn(
    const _Float16* __restrict__ Q, const _Float16* __restrict__ K,
    const _Float16* __restrict__ Vt,
    _Float16* __restrict__ Ctx)
{
    __shared__ __align__(16) _Float16 Ks[2][KVB * HDIM];   // 2 x 16KB
    __shared__ __align__(16) _Float16 Vs[3][HDIM * KVB];   // 3 x 16KB

    const int tid  = threadIdx.x;
    const int wave = tid >> 6;
    const int lane = tid & 63;
    const int li   = lane & 15;
    const int quad = lane >> 4;

    // XCD-grouping swizzle: nwg = 16*32 = 512, cpx = 64. 16 q-tile blocks
    // sharing a bh K/V panel land on the same XCD's L2.
    const int bid = blockIdx.x + 16 * blockIdx.y;
    const int swz = (bid & 7) * 64 + (bid >> 3);
    const int q0  = (swz & 15) * 128;
    const int bh  = swz >> 4;
    const int b   = bh >> 4, h = bh & 15;

    half8 qa[2][2];
    #pragma unroll
    for (int nq = 0; nq < 2; ++nq) {
        size_t qrow = ((size_t)bh * SEQ + q0 + wave * 32 + nq * 16 + li) * HDIM;
        qa[nq][0] = *(const half8*)(Q + qrow + quad * 8);
        qa[nq][1] = *(const half8*)(Q + qrow + 32 + quad * 8);
    }

    // ones A-fragment: row 0 (li==0) = 1.0 -> accumulator row0 = row-sums
    half8 onesA;
    {
        _Float16 v = (li == 0) ? (_Float16)1.0f : (_Float16)0.0f;
        #pragma unroll
        for (int c = 0; c < 8; ++c) onesA[c] = v;
    }

    floatx4 O[4][2];
    floatx4 rsacc[2];
    #pragma unroll
    for (int nq = 0; nq < 2; ++nq) {
        rsacc[nq] = (floatx4){0.f, 0.f, 0.f, 0.f};
        #pragma unroll
        for (int i = 0; i < 4; ++i) O[i][nq] = (floatx4){0.f, 0.f, 0.f, 0.f};
    }

    const _Float16* Kbh = K  + (size_t)bh * SEQ * HDIM;
    const _Float16* Vbh = Vt + (size_t)bh * HDIM * SEQ;

    // K tile [128][64] halfs, chunk src-swizzled by r&7 (as before).
    // V tile [64][128] halfs: 16 chunks/row, src-swizzled by r&15 so the
    // PV read (chunk ^ li) spreads uniformly over all bank groups.
    auto stage = [&](_Float16* Kl, _Float16* Vl, int kt_) {
        const _Float16* Kg = Kbh + (size_t)kt_ * KVB * HDIM;
        const _Float16* Vg = Vbh + kt_ * KVB;
        #pragma unroll
        for (int p = 0; p < 4; ++p) {
            int s = tid + p * 256;
            int r = s >> 3, ks = s & 7;
            int kg = (ks ^ (r & 7)) << 3;
            gload16(Kg + r * HDIM + kg, Kl + s * 8);
        }
        #pragma unroll
        for (int p = 0; p < 4; ++p) {
            int s = tid + p * 256;
            int r = s >> 4, ks = s & 15;
            int kg = (ks ^ (r & 15)) << 3;
            gload16(Vg + (size_t)r * SEQ + kg, Vl + s * 8);
        }
    };

    // QK^T -> exp -> permlane -> pbN (tile kt; K from LDS, 8 mb blocks)
    auto qk_phase = [&](const _Float16* Kc, half8 (&pbN)[2][4]) {
        unsigned R[2][8][2];
        #pragma unroll
        for (int mb = 0; mb < 8; ++mb) {
            int row = (mb * 16 + li) << 6;
            half8 a0 = *(const half8*)(Kc + row + ((quad ^ (li & 7)) << 3));
            half8 a1 = *(const half8*)(Kc + row + (((quad + 4) ^ (li & 7)) << 3));
            #pragma unroll
            for (int nq = 0; nq < 2; ++nq) {
                floatx4 st = (floatx4){-SOFT_C, -SOFT_C, -SOFT_C, -SOFT_C};
                st = __builtin_amdgcn_mfma_f32_16x16x32_f16(a0, qa[nq][0], st, 0, 0, 0);
                st = __builtin_amdgcn_mfma_f32_16x16x32_f16(a1, qa[nq][1], st, 0, 0, 0);
                R[nq][mb][0] = pk2(EXP2F(st[0]), EXP2F(st[1]));
                R[nq][mb][1] = pk2(EXP2F(st[2]), EXP2F(st[3]));
            }
        }
        #pragma unroll
        for (int nq = 0; nq < 2; ++nq)
            #pragma unroll
            for (int kc = 0; kc < 4; ++kc) {
                unsigned w0, w1, w2, w3;
                {
                    unsigned x = R[nq][2 * kc][0], y = R[nq][2 * kc + 1][0];
                    plswap(x, y);
                    w0 = x; w2 = y;
                }
                {
                    unsigned x = R[nq][2 * kc][1], y = R[nq][2 * kc + 1][1];
                    plswap(x, y);
                    w1 = x; w3 = y;
                }
                uint4v uw; uw[0] = w0; uw[1] = w1; uw[2] = w2; uw[3] = w3;
                pbN[nq][kc] = __builtin_bit_cast(half8, uw);
            }
    };

    // rowsum + PV of the previous tile; V-frags straight from LDS tri-buf.
    auto pv_phase = [&](half8 (&pbP)[2][4], const _Float16* Vc) {
        #pragma unroll
        for (int nq = 0; nq < 2; ++nq)
            #pragma unroll
            for (int kc = 0; kc < 4; ++kc)
                rsacc[nq] = __builtin_amdgcn_mfma_f32_16x16x32_f16(onesA, pbP[nq][kc], rsacc[nq], 0, 0, 0);
        #pragma unroll
        for (int mb = 0; mb < 4; ++mb) {
            int rowb = (mb * 16 + li) * KVB;
            #pragma unroll
            for (int kc = 0; kc < 4; ++kc) {
                half8 vf = *(const half8*)(Vc + rowb + ((((kc * 4 + quad) ^ li)) << 3));
                #pragma unroll
                for (int nq = 0; nq < 2; ++nq)
                    O[mb][nq] = __builtin_amdgcn_mfma_f32_16x16x32_f16(vf, pbP[nq][kc], O[mb][nq], 0, 0, 0);
            }
        }
    };

    half8 pbA[2][4], pbB[2][4];

    stage(&Ks[0][0], &Vs[0][0], 0);
    __syncthreads();                       // tile 0 ready

    // phase 0: QK(0) -> pbA ; stage tile 1
    stage(&Ks[1][0], &Vs[1][0], 1);
    __builtin_amdgcn_s_setprio(1);
    qk_phase(&Ks[0][0], pbA);
    __builtin_amdgcn_s_setprio(0);
    __syncthreads();                       // tile 1 ready

    // invariant before phase kt: va=V(kt-1), vb=V(kt), vc=free
    _Float16* va = &Vs[0][0];
    _Float16* vb = &Vs[1][0];
    _Float16* vc = &Vs[2][0];

    for (int kt = 1; kt < NKT2 - 1; kt += 2) {
        // phase kt (odd): QK from Ks[1]; stage kt+1 -> Ks[0], vc
        stage(&Ks[0][0], vc, kt + 1);
        __builtin_amdgcn_s_setprio(1);
        pv_phase(pbA, va);                 // tile kt-1
        qk_phase(&Ks[1][0], pbB);          // tile kt
        __builtin_amdgcn_s_setprio(0);
        __syncthreads();
        { _Float16* t = va; va = vb; vb = vc; vc = t; }

        // phase kt+1 (even): QK from Ks[0]; stage kt+2 -> Ks[1], vc
        stage(&Ks[1][0], vc, kt + 2);
        __builtin_amdgcn_s_setprio(1);
        pv_phase(pbB, va);                 // tile kt
        qk_phase(&Ks[0][0], pbA);          // tile kt+1
        __builtin_amdgcn_s_setprio(0);
        __syncthreads();
        { _Float16* t = va; va = vb; vb = vc; vc = t; }
    }

    // phase 15 (last, odd): no stage; drain
    __builtin_amdgcn_s_setprio(1);
    pv_phase(pbA, va);                     // tile 14
    qk_phase(&Ks[1][0], pbB);              // tile 15
    pv_phase(pbB, vb);                     // tile 15
    __builtin_amdgcn_s_setprio(0);
    __syncthreads();                       // all waves done with K/V LDS

    // full row sums: accumulator row 0 = (quad 0, reg 0), col = query li.
    // Broadcast to all quads of the same li, then normalize in-register.
    float inv[2];
    #pragma unroll
    for (int nq = 0; nq < 2; ++nq) {
        float rs = __shfl(rsacc[nq][0], li, 64);
        inv[nq] = 1.0f / rs;
    }

    // normalized O^T -> XOR-swizzled stride-64 transpose in dead Ks[0]
    // (4KB scratch per wave, 4 waves = exactly Ks[0]), coalesced stores.
    _Float16* Sw = &Ks[0][0] + wave * (32 * 64);
    #pragma unroll
    for (int mb = 0; mb < 4; ++mb)
        #pragma unroll
        for (int nq = 0; nq < 2; ++nq) {
            uint2 w;
            w.x = pk2(O[mb][nq][0] * inv[nq], O[mb][nq][1] * inv[nq]);
            w.y = pk2(O[mb][nq][2] * inv[nq], O[mb][nq][3] * inv[nq]);
            int row = nq * 16 + li;             // q within wave tile
            int col = mb * 16 + quad * 4;       // hd
            int swc = (((col >> 3) ^ (row & 7)) << 3) | (col & 7);
            *(uint2*)(Sw + row * 64 + swc) = w;
        }
    __builtin_amdgcn_s_waitcnt(0);   // own ds_writes complete (wave-local)
    #pragma unroll
    for (int p = 0; p < 4; ++p) {
        int idx = p * 64 + lane;
        int qq = idx >> 3, c = idx & 7;
        half8 v = *(const half8*)(Sw + qq * 64 + ((c ^ (qq & 7)) << 3));
        size_t row = (size_t)b * SEQ + q0 + wave * 32 + qq;
        *(half8*)(Ctx + row * DIM + h * HDIM + c * 8) = v;
    }
}

// ---------------- Output projection: 64x128 tiles, dbuf BK=64 -------------
// grid (8, 64) = 512 blocks -> 2-3 blocks/CU. Waves 2x2, each 32x64
// (acc[2][4]). LDS 48KB: A0 8 | B0 16 | A1 8 | B1 16. 1 barrier/step.
__global__ __launch_bounds__(256, 3) void out_mfma(
    const _Float16* __restrict__ Ctx, const _Float16* __restrict__ Wot,
    const float* __restrict__ bo, float* __restrict__ out)
{
    __shared__ __align__(16) _Float16 SH[24576];   // 48KB

    // XCD swizzle: nwg = 512, cpx = 64; per XCD: by in one 8-group, all bx
    // -> 8 A-panels (1MB) + full Wot (2MB) < 4MB L2.
    const int bid = blockIdx.x + 8 * blockIdx.y;
    const int swz = (bid & 7) * 64 + (bid >> 3);
    const int bx = swz & 7, by = swz >> 3;
    const int m0 = by * 64, n0 = bx * 128;

    const int tid  = threadIdx.x;
    const int wave = tid >> 6;
    const int lane = tid & 63;
    const int li   = lane & 15;
    const int quad = lane >> 4;
    const int wm   = (wave >> 1) * 32;
    const int wn   = (wave & 1) * 64;

    _Float16* A0 = SH;
    _Float16* B0 = SH + 4096;
    _Float16* A1 = SH + 12288;
    _Float16* B1 = SH + 16384;

    floatx4 acc[2][4];
    #pragma unroll
    for (int i = 0; i < 2; ++i)
        #pragma unroll
        for (int j = 0; j < 4; ++j) acc[i][j] = (floatx4){0.f, 0.f, 0.f, 0.f};

    auto stg = [&](int k0, _Float16* AL, _Float16* BL) {
        #pragma unroll
        for (int p = 0; p < 2; ++p) {        // A: 64 rows x 64 k = 8KB
            int s = tid + p * 256;
            int r = s >> 3, ks = s & 7;
            int kg = (ks ^ (r & 7)) << 3;
            gload16(Ctx + (size_t)(m0 + r) * DIM + k0 + kg,
                    AL + (wave * 64 + p * 256) * 8);
        }
        #pragma unroll
        for (int p = 0; p < 4; ++p) {        // B: 128 rows x 64 k = 16KB
            int s = tid + p * 256;
            int r = s >> 3, ks = s & 7;
            int kg = (ks ^ (r & 7)) << 3;
            gload16(Wot + (size_t)(n0 + r) * DIM + k0 + kg,
                    BL + (wave * 64 + p * 256) * 8);
        }
    };

    auto cmp = [&](const _Float16* AL, const _Float16* BL) {
        half8 a[2][2], b[4][2];
        #pragma unroll
        for (int i = 0; i < 2; ++i) {
            int ra = (wm + i * 16 + li) << 6;
            #pragma unroll
            for (int hh = 0; hh < 2; ++hh)
                a[i][hh] = *(const half8*)(AL + ra + (((hh * 4 + quad) ^ (li & 7)) << 3));
        }
        #pragma unroll
        for (int j = 0; j < 4; ++j) {
            int rb = (wn + j * 16 + li) << 6;
            #pragma unroll
            for (int hh = 0; hh < 2; ++hh)
                b[j][hh] = *(const half8*)(BL + rb + (((hh * 4 + quad) ^ (li & 7)) << 3));
        }
        #pragma unroll
        for (int i = 0; i < 2; ++i)
            #pragma unroll
            for (int j = 0; j < 4; ++j) {
                acc[i][j] = __builtin_amdgcn_mfma_f32_16x16x32_f16(a[i][0], b[j][0], acc[i][j], 0, 0, 0);
                acc[i][j] = __builtin_amdgcn_mfma_f32_16x16x32_f16(a[i][1], b[j][1], acc[i][j], 0, 0, 0);
            }
    };

    stg(0, A0, B0);
    __syncthreads();
    for (int kt = 0; kt < DIM / 64; kt += 2) {
        stg((kt + 1) * 64, A1, B1);
        __builtin_amdgcn_s_setprio(1);
        cmp(A0, B0);
        __builtin_amdgcn_s_setprio(0);
        __syncthreads();
        if (kt + 2 < DIM / 64) stg((kt + 2) * 64, A0, B0);
        __builtin_amdgcn_s_setprio(1);
        cmp(A1, B1);
        __builtin_amdgcn_s_setprio(0);
        __syncthreads();
    }

    #pragma unroll
    for (int i = 0; i < 2; ++i)
        #pragma unroll
        for (int j = 0; j < 4; ++j) {
            int n = n0 + wn + j * 16 + li;
            float b_ = bo[n];
            #pragma unroll
            for (int r = 0; r < 4; ++r) {
                int m = m0 + wm + i * 16 + quad * 4 + r;
                out[(size_t)m * DIM + n] = acc[i][j][r] + b_;
            }
        }
}

extern "C" void kernel_launch(void* const* d_in, const int* in_sizes, int n_in,
                              void* d_out, int out_size, void* d_ws, size_t ws_size,
                              hipStream_t stream) {
    const float* x  = (const float*)d_in[0];
    const float* Wq = (const float*)d_in[1];
    const float* bq = (const float*)d_in[2];
    const float* Wk = (const float*)d_in[3];
    const float* bk = (const float*)d_in[4];
    const float* Wv = (const float*)d_in[5];
    const float* bv = (const float*)d_in[6];
    const float* Wo = (const float*)d_in[7];
    const float* bo = (const float*)d_in[8];
    float* out = (float*)d_out;

    const size_t PX = (size_t)MROWS * DIM;   // 4M
    const size_t PW = (size_t)DIM * DIM;     // 1M
    _Float16* xh  = (_Float16*)d_ws;         // later Ctx
    _Float16* Wqt = xh + PX;
    _Float16* Wkt = Wqt + PW;
    _Float16* Wvt = Wkt + PW;
    _Float16* Wot = Wvt + PW;
    _Float16* Qh  = Wot + PW;
    _Float16* Kh  = Qh + PX;
    _Float16* spare = Kh + PX;
    _Float16* Vth = spare + PX;

    _Float16* Ctx = xh;

    prep<<<dim3(16, 16, 5), 256, 0, stream>>>(
        x, Wq, Wk, Wv, Wo, xh, Wqt, Wkt, Wvt, Wot);

    qkv_mfma<<<dim3(DIM / 128, MROWS / 128, 3), 256, 0, stream>>>(
        xh, Wqt, Wkt, Wvt, bq, bk, bv, Qh, Kh, Vth);

    attn<<<dim3(SEQ / 128, BH), 256, 0, stream>>>(
        Qh, Kh, Vth, Ctx);

    out_mfma<<<dim3(8, MROWS / 64), 256, 0, stream>>>(
        Ctx, Wot, bo, out);
}